// Round 4
// baseline (609.051 us; speedup 1.0000x reference)
//
#include <hip/hip_runtime.h>
#include <hip/hip_bf16.h>

// Problem constants: T=1024, B=8, D=1024, N_HEAD=16, D_HEAD=64
// I/O dtype: fp32 (per reference). Internal compute: bf16 MFMA with fp32 accum.
// heads buffer layout: [T*B][3072] bf16, cols [0,1024)=Q, [1024,2048)=K, [2048,3072)=V

typedef __bf16 v8bf __attribute__((ext_vector_type(8)));
typedef float  v4f  __attribute__((ext_vector_type(4)));
typedef unsigned short v8us __attribute__((ext_vector_type(8)));

#define MFMA16x16x32(a, b, c) __builtin_amdgcn_mfma_f32_16x16x32_bf16(a, b, c, 0, 0, 0)

__device__ __forceinline__ unsigned short f2bf(float f) {
    unsigned int u = __float_as_uint(f);
    u = (u + 0x7FFF + ((u >> 16) & 1)) >> 16;   // RNE
    return (unsigned short)u;
}

// ---------------- prep: x_bf16 = bf16(input_f32 + pos_enc_f32) ----------------
__global__ __launch_bounds__(256) void prep_x(const float* __restrict__ in,
                                              const float* __restrict__ pe,
                                              unsigned short* __restrict__ x) {
    size_t idx = ((size_t)blockIdx.x * 256 + threadIdx.x) * 8;
    v4f a0 = *(const v4f*)(in + idx);
    v4f a1 = *(const v4f*)(in + idx + 4);
    v4f p0 = *(const v4f*)(pe + idx);
    v4f p1 = *(const v4f*)(pe + idx + 4);
    v8us r;
    unsigned short* rp = (unsigned short*)&r;
#pragma unroll
    for (int q = 0; q < 4; q++) {
        rp[q]     = f2bf(a0[q] + p0[q]);
        rp[q + 4] = f2bf(a1[q] + p1[q]);
    }
    *(v8us*)(x + idx) = r;
}

// -------- tiled transpose + cast: src_f32[R][C] -> dst_bf16[C][R] ----------
__global__ __launch_bounds__(256) void transpose_f32_bf16(const float* __restrict__ src,
                                                          unsigned short* __restrict__ dst,
                                                          int R, int C) {
    __shared__ alignas(16) unsigned short t[64][72];
    int c0 = blockIdx.x * 64, r0 = blockIdx.y * 64;
    int tid = threadIdx.x;
    int rr = tid >> 2, cg = (tid & 3) * 16;
    const float* s = src + (size_t)(r0 + rr) * C + c0 + cg;
#pragma unroll
    for (int q4 = 0; q4 < 4; q4++) {
        v4f v = *(const v4f*)(s + q4 * 4);
#pragma unroll
        for (int q = 0; q < 4; q++) t[rr][cg + q4 * 4 + q] = f2bf(v[q]);
    }
    __syncthreads();
    v8us o0, o1;
    unsigned short* o0p = (unsigned short*)&o0;
    unsigned short* o1p = (unsigned short*)&o1;
#pragma unroll
    for (int q = 0; q < 8; q++) {
        o0p[q] = t[cg + q][rr];
        o1p[q] = t[cg + 8 + q][rr];
    }
    *(v8us*)(dst + (size_t)(c0 + rr) * R + r0 + cg)     = o0;
    *(v8us*)(dst + (size_t)(c0 + rr) * R + r0 + cg + 8) = o1;
}

// ---------------- GEMM: C[M][N] = A[M][K] * Bt[N][K]^T, bf16 in, fp32 acc --------
// 128x128 tile, BK=32, 4 waves (each 64x64) — m93-pattern. F32OUT: fp32 C, else bf16 C.
template <bool F32OUT>
__global__ __launch_bounds__(256) void gemm_bf16(const unsigned short* __restrict__ A,
                                                 const unsigned short* __restrict__ Bt,
                                                 void* __restrict__ Cout,
                                                 int M, int N, int K) {
    __shared__ alignas(16) unsigned short As[128][40];
    __shared__ alignas(16) unsigned short Bs[128][40];
    const int tid = threadIdx.x;
    const int lane = tid & 63, wave = tid >> 6;
    const int quad = lane >> 4, lq = lane & 15;
    const int m0 = blockIdx.y * 128, n0 = blockIdx.x * 128;
    const int mW = (wave & 1) * 64, nW = (wave >> 1) * 64;

    v4f acc[4][4];
#pragma unroll
    for (int mi = 0; mi < 4; mi++)
#pragma unroll
        for (int ni = 0; ni < 4; ni++) acc[mi][ni] = (v4f){0.f, 0.f, 0.f, 0.f};

    const int srow = tid >> 1, shalf = (tid & 1) * 16;
    const unsigned short* ag = A  + (size_t)(m0 + srow) * K + shalf;
    const unsigned short* bg = Bt + (size_t)(n0 + srow) * K + shalf;

    for (int k0 = 0; k0 < K; k0 += 32) {
        v8us a0 = *(const v8us*)(ag + k0);
        v8us a1 = *(const v8us*)(ag + k0 + 8);
        v8us b0 = *(const v8us*)(bg + k0);
        v8us b1 = *(const v8us*)(bg + k0 + 8);
        __syncthreads();
        *(v8us*)&As[srow][shalf]     = a0;
        *(v8us*)&As[srow][shalf + 8] = a1;
        *(v8us*)&Bs[srow][shalf]     = b0;
        *(v8us*)&Bs[srow][shalf + 8] = b1;
        __syncthreads();
        v8bf af[4], bfr[4];
#pragma unroll
        for (int mi = 0; mi < 4; mi++) af[mi]  = *(const v8bf*)&As[mW + mi * 16 + lq][quad * 8];
#pragma unroll
        for (int ni = 0; ni < 4; ni++) bfr[ni] = *(const v8bf*)&Bs[nW + ni * 16 + lq][quad * 8];
#pragma unroll
        for (int mi = 0; mi < 4; mi++)
#pragma unroll
            for (int ni = 0; ni < 4; ni++)
                acc[mi][ni] = MFMA16x16x32(af[mi], bfr[ni], acc[mi][ni]);
    }

#pragma unroll
    for (int mi = 0; mi < 4; mi++)
#pragma unroll
        for (int ni = 0; ni < 4; ni++)
#pragma unroll
            for (int r = 0; r < 4; r++) {
                int row = m0 + mW + mi * 16 + quad * 4 + r;
                int col = n0 + nW + ni * 16 + lq;
                if (F32OUT)
                    ((float*)Cout)[(size_t)row * N + col] = acc[mi][ni][r];
                else
                    ((unsigned short*)Cout)[(size_t)row * N + col] = f2bf(acc[mi][ni][r]);
            }
}

// ---------------- attention constants ----------------
#define AT_T  1024
#define AT_B  8
#define AT_NH 16
#define AT_HS 3072
#define AT_ALPHA 0.18033688011112042f  // (1/8) * log2(e)

// ---------------- fused attention: one wave per (b, n, 16-row i-tile) ----------------
__global__ __launch_bounds__(64) void attn_fused(const unsigned short* __restrict__ heads,
                                                 unsigned short* __restrict__ av,
                                                 float* __restrict__ mBuf,
                                                 float* __restrict__ lBuf) {
    __shared__ alignas(16) unsigned short Ps[16][40];
    const int bn = blockIdx.x, b = bn >> 4, n = bn & 15;
    const int lane = threadIdx.x, quad = lane >> 4, lq = lane & 15;
    const int i0 = blockIdx.y * 16;

    size_t qbase = ((size_t)(i0 + lq) * 8 + b) * AT_HS + n * 64 + quad * 8;
    v8bf q0 = *(const v8bf*)(heads + qbase);
    v8bf q1 = *(const v8bf*)(heads + qbase + 32);

    // ---- pass 1: per-row max & sum (exp2 domain) ----
    float M[4], S[4];
#pragma unroll
    for (int r = 0; r < 4; r++) { M[r] = -1e30f; S[r] = 0.f; }

    for (int j0 = 0; j0 <= i0; j0 += 16) {
        size_t kbase = ((size_t)(j0 + lq) * 8 + b) * AT_HS + 1024 + n * 64 + quad * 8;
        v8bf k0 = *(const v8bf*)(heads + kbase);
        v8bf k1 = *(const v8bf*)(heads + kbase + 32);
        v4f s = (v4f){0.f, 0.f, 0.f, 0.f};
        s = MFMA16x16x32(q0, k0, s);
        s = MFMA16x16x32(q1, k1, s);
        int j = j0 + lq;
#pragma unroll
        for (int r = 0; r < 4; r++) {
            int i = i0 + quad * 4 + r;
            if (j <= i) {
                float v = s[r] * AT_ALPHA;
                float Mn = fmaxf(M[r], v);
                S[r] = S[r] * exp2f(M[r] - Mn) + exp2f(v - Mn);
                M[r] = Mn;
            }
        }
    }
#pragma unroll
    for (int mask = 1; mask < 16; mask <<= 1) {
#pragma unroll
        for (int r = 0; r < 4; r++) {
            float Mo = __shfl_xor(M[r], mask);
            float So = __shfl_xor(S[r], mask);
            float Mn = fmaxf(M[r], Mo);
            S[r] = S[r] * exp2f(M[r] - Mn) + So * exp2f(Mo - Mn);
            M[r] = Mn;
        }
    }
    float linv[4];
#pragma unroll
    for (int r = 0; r < 4; r++) linv[r] = __builtin_amdgcn_rcpf(S[r]);
    if (lq == 0) {
#pragma unroll
        for (int r = 0; r < 4; r++) {
            int i = i0 + quad * 4 + r;
            mBuf[(size_t)bn * AT_T + i] = M[r];
            lBuf[(size_t)bn * AT_T + i] = S[r];
        }
    }

    // ---- pass 2: O = P V over 32-j chunks ----
    v4f o[4];
#pragma unroll
    for (int dt = 0; dt < 4; dt++) o[dt] = (v4f){0.f, 0.f, 0.f, 0.f};

    for (int j0 = 0; j0 < i0 + 16; j0 += 32) {
#pragma unroll
        for (int jt = 0; jt < 2; jt++) {
            int jb = j0 + jt * 16;
            size_t kbase = ((size_t)(jb + lq) * 8 + b) * AT_HS + 1024 + n * 64 + quad * 8;
            v8bf k0 = *(const v8bf*)(heads + kbase);
            v8bf k1 = *(const v8bf*)(heads + kbase + 32);
            v4f s = (v4f){0.f, 0.f, 0.f, 0.f};
            s = MFMA16x16x32(q0, k0, s);
            s = MFMA16x16x32(q1, k1, s);
            int j = jb + lq;
#pragma unroll
            for (int r = 0; r < 4; r++) {
                int i = i0 + quad * 4 + r;
                float val = (j <= i) ? exp2f(s[r] * AT_ALPHA - M[r]) * linv[r] : 0.f;
                Ps[quad * 4 + r][jt * 16 + lq] = f2bf(val);
            }
        }
        __syncthreads();
        v8bf pf = *(const v8bf*)&Ps[lq][quad * 8];
#pragma unroll
        for (int dt = 0; dt < 4; dt++) {
            v8bf vf;
            unsigned short* vp = (unsigned short*)&vf;
#pragma unroll
            for (int jj = 0; jj < 8; jj++) {
                int j = j0 + quad * 8 + jj;
                vp[jj] = heads[((size_t)j * 8 + b) * AT_HS + 2048 + n * 64 + dt * 16 + lq];
            }
            o[dt] = MFMA16x16x32(pf, vf, o[dt]);
        }
        __syncthreads();   // Ps reused next chunk
    }

#pragma unroll
    for (int dt = 0; dt < 4; dt++)
#pragma unroll
        for (int r = 0; r < 4; r++) {
            int i = i0 + quad * 4 + r;
            av[((size_t)i * 8 + b) * 1024 + n * 64 + dt * 16 + lq] = f2bf(o[dt][r]);
        }
}

// ---------------- coverage[b][j][i] = mean_n prob[b,n,i,j], fp32 out ----------------
__global__ __launch_bounds__(64) void coverage_k(const unsigned short* __restrict__ heads,
                                                 const float* __restrict__ mBuf,
                                                 const float* __restrict__ lBuf,
                                                 float* __restrict__ cov) {
    const int jt = blockIdx.x, it = blockIdx.y, b = blockIdx.z;
    const int lane = threadIdx.x, quad = lane >> 4, lq = lane & 15;
    const int i0 = it * 16, j0 = jt * 16;
    if (jt > it) {  // future block: coverage = 0
#pragma unroll
        for (int r = 0; r < 4; r++) {
            int jl = quad * 4 + r;
            cov[(size_t)b * 1048576 + (size_t)(j0 + jl) * 1024 + i0 + lq] = 0.f;
        }
        return;
    }
    float acc4[4] = {0.f, 0.f, 0.f, 0.f};
    for (int n = 0; n < 16; n++) {
        int bn = b * 16 + n;
        size_t qbase = ((size_t)(i0 + lq) * 8 + b) * AT_HS + n * 64 + quad * 8;
        v8bf q0 = *(const v8bf*)(heads + qbase);
        v8bf q1 = *(const v8bf*)(heads + qbase + 32);
        size_t kbase = ((size_t)(j0 + lq) * 8 + b) * AT_HS + 1024 + n * 64 + quad * 8;
        v8bf k0 = *(const v8bf*)(heads + kbase);
        v8bf k1 = *(const v8bf*)(heads + kbase + 32);
        v4f s = (v4f){0.f, 0.f, 0.f, 0.f};
        s = MFMA16x16x32(q0, k0, s);
        s = MFMA16x16x32(q1, k1, s);
        int j = j0 + lq;
#pragma unroll
        for (int r = 0; r < 4; r++) {
            int i = i0 + quad * 4 + r;
            if (j <= i) {
                float m = mBuf[(size_t)bn * AT_T + i];
                float l = lBuf[(size_t)bn * AT_T + i];
                acc4[r] += exp2f(s[r] * AT_ALPHA - m) * __builtin_amdgcn_rcpf(l);
            }
        }
    }
    __shared__ alignas(16) float ct[16][17];
#pragma unroll
    for (int r = 0; r < 4; r++) ct[quad * 4 + r][lq] = acc4[r] * 0.0625f;
    __syncthreads();
#pragma unroll
    for (int r = 0; r < 4; r++) {
        int jl = quad * 4 + r;
        float v = ct[lq][jl];
        cov[(size_t)b * 1048576 + (size_t)(j0 + jl) * 1024 + i0 + lq] = v;
    }
}

// ---------------- launch ----------------
extern "C" void kernel_launch(void* const* d_in, const int* in_sizes, int n_in,
                              void* d_out, int out_size, void* d_ws, size_t ws_size,
                              hipStream_t stream) {
    const float* input = (const float*)d_in[0];
    const float* pos   = (const float*)d_in[1];
    // d_in[2] = attn_mask (deterministic causal; ignored)
    const float* Wqkv  = (const float*)d_in[3];
    const float* Wo    = (const float*)d_in[4];
    float* out = (float*)d_out;

    // workspace layout (bytes)
    char* ws = (char*)d_ws;
    if (ws_size < 93323264) return;  // need ~89 MB
    unsigned short* x     = (unsigned short*)(ws);               // 16,777,216 B
    unsigned short* heads = (unsigned short*)(ws + 16777216);    // 50,331,648 B
    unsigned short* av    = (unsigned short*)(ws + 67108864);    // 16,777,216 B
    unsigned short* WqkvT = (unsigned short*)(ws + 83886080);    //  6,291,456 B
    unsigned short* WoT   = (unsigned short*)(ws + 90177536);    //  2,097,152 B
    float* mBuf = (float*)(ws + 92274688);                       //    524,288 B
    float* lBuf = (float*)(ws + 92798976);                       //    524,288 B

    prep_x<<<4096, 256, 0, stream>>>(input, pos, x);
    transpose_f32_bf16<<<dim3(48, 16), 256, 0, stream>>>(Wqkv, WqkvT, 1024, 3072);
    transpose_f32_bf16<<<dim3(16, 16), 256, 0, stream>>>(Wo, WoT, 1024, 1024);
    gemm_bf16<false><<<dim3(24, 64), 256, 0, stream>>>(x, WqkvT, heads, 8192, 3072, 1024);
    attn_fused<<<dim3(128, 64), 64, 0, stream>>>(heads, av, mBuf, lBuf);
    coverage_k<<<dim3(64, 64, 8), 64, 0, stream>>>(heads, mBuf, lBuf, out + 8388608);
    gemm_bf16<true><<<dim3(8, 64), 256, 0, stream>>>(av, WoT, out, 8192, 1024, 1024);
}

// Round 5
// 555.438 us; speedup vs baseline: 1.0965x; 1.0965x over previous
//
#include <hip/hip_runtime.h>
#include <hip/hip_bf16.h>

// Problem constants: T=1024, B=8, D=1024, N_HEAD=16, D_HEAD=64
// I/O dtype: fp32 (per reference). Internal compute: bf16 MFMA with fp32 accum.
// heads buffer layout: [T*B][3072] bf16, cols [0,1024)=Q, [1024,2048)=K, [2048,3072)=V

typedef __bf16 v8bf __attribute__((ext_vector_type(8)));
typedef float  v4f  __attribute__((ext_vector_type(4)));
typedef unsigned short v8us __attribute__((ext_vector_type(8)));

#define MFMA16x16x32(a, b, c) __builtin_amdgcn_mfma_f32_16x16x32_bf16(a, b, c, 0, 0, 0)

__device__ __forceinline__ unsigned short f2bf(float f) {
    unsigned int u = __float_as_uint(f);
    u = (u + 0x7FFF + ((u >> 16) & 1)) >> 16;   // RNE
    return (unsigned short)u;
}

// ---------------- prep: x_bf16 = bf16(input_f32 + pos_enc_f32) ----------------
__global__ __launch_bounds__(256) void prep_x(const float* __restrict__ in,
                                              const float* __restrict__ pe,
                                              unsigned short* __restrict__ x) {
    size_t idx = ((size_t)blockIdx.x * 256 + threadIdx.x) * 8;
    v4f a0 = *(const v4f*)(in + idx);
    v4f a1 = *(const v4f*)(in + idx + 4);
    v4f p0 = *(const v4f*)(pe + idx);
    v4f p1 = *(const v4f*)(pe + idx + 4);
    v8us r;
    unsigned short* rp = (unsigned short*)&r;
#pragma unroll
    for (int q = 0; q < 4; q++) {
        rp[q]     = f2bf(a0[q] + p0[q]);
        rp[q + 4] = f2bf(a1[q] + p1[q]);
    }
    *(v8us*)(x + idx) = r;
}

// -------- tiled transpose + cast: src_f32[R][C] -> dst_bf16[C][R] ----------
__global__ __launch_bounds__(256) void transpose_f32_bf16(const float* __restrict__ src,
                                                          unsigned short* __restrict__ dst,
                                                          int R, int C) {
    __shared__ alignas(16) unsigned short t[64][72];
    int c0 = blockIdx.x * 64, r0 = blockIdx.y * 64;
    int tid = threadIdx.x;
    int rr = tid >> 2, cg = (tid & 3) * 16;
    const float* s = src + (size_t)(r0 + rr) * C + c0 + cg;
#pragma unroll
    for (int q4 = 0; q4 < 4; q4++) {
        v4f v = *(const v4f*)(s + q4 * 4);
#pragma unroll
        for (int q = 0; q < 4; q++) t[rr][cg + q4 * 4 + q] = f2bf(v[q]);
    }
    __syncthreads();
    v8us o0, o1;
    unsigned short* o0p = (unsigned short*)&o0;
    unsigned short* o1p = (unsigned short*)&o1;
#pragma unroll
    for (int q = 0; q < 8; q++) {
        o0p[q] = t[cg + q][rr];
        o1p[q] = t[cg + 8 + q][rr];
    }
    *(v8us*)(dst + (size_t)(c0 + rr) * R + r0 + cg)     = o0;
    *(v8us*)(dst + (size_t)(c0 + rr) * R + r0 + cg + 8) = o1;
}

// ---------------- GEMM: C[M][N] = A[M][K] * Bt[N][K]^T, bf16 in, fp32 acc --------
// 128x128 tile, BK=32, 4 waves (each 64x64) — m93-pattern. F32OUT: fp32 C, else bf16 C.
template <bool F32OUT>
__global__ __launch_bounds__(256) void gemm_bf16(const unsigned short* __restrict__ A,
                                                 const unsigned short* __restrict__ Bt,
                                                 void* __restrict__ Cout,
                                                 int M, int N, int K) {
    __shared__ alignas(16) unsigned short As[128][40];
    __shared__ alignas(16) unsigned short Bs[128][40];
    const int tid = threadIdx.x;
    const int lane = tid & 63, wave = tid >> 6;
    const int quad = lane >> 4, lq = lane & 15;
    const int m0 = blockIdx.y * 128, n0 = blockIdx.x * 128;
    const int mW = (wave & 1) * 64, nW = (wave >> 1) * 64;

    v4f acc[4][4];
#pragma unroll
    for (int mi = 0; mi < 4; mi++)
#pragma unroll
        for (int ni = 0; ni < 4; ni++) acc[mi][ni] = (v4f){0.f, 0.f, 0.f, 0.f};

    const int srow = tid >> 1, shalf = (tid & 1) * 16;
    const unsigned short* ag = A  + (size_t)(m0 + srow) * K + shalf;
    const unsigned short* bg = Bt + (size_t)(n0 + srow) * K + shalf;

    for (int k0 = 0; k0 < K; k0 += 32) {
        v8us a0 = *(const v8us*)(ag + k0);
        v8us a1 = *(const v8us*)(ag + k0 + 8);
        v8us b0 = *(const v8us*)(bg + k0);
        v8us b1 = *(const v8us*)(bg + k0 + 8);
        __syncthreads();
        *(v8us*)&As[srow][shalf]     = a0;
        *(v8us*)&As[srow][shalf + 8] = a1;
        *(v8us*)&Bs[srow][shalf]     = b0;
        *(v8us*)&Bs[srow][shalf + 8] = b1;
        __syncthreads();
        v8bf af[4], bfr[4];
#pragma unroll
        for (int mi = 0; mi < 4; mi++) af[mi]  = *(const v8bf*)&As[mW + mi * 16 + lq][quad * 8];
#pragma unroll
        for (int ni = 0; ni < 4; ni++) bfr[ni] = *(const v8bf*)&Bs[nW + ni * 16 + lq][quad * 8];
#pragma unroll
        for (int mi = 0; mi < 4; mi++)
#pragma unroll
            for (int ni = 0; ni < 4; ni++)
                acc[mi][ni] = MFMA16x16x32(af[mi], bfr[ni], acc[mi][ni]);
    }

#pragma unroll
    for (int mi = 0; mi < 4; mi++)
#pragma unroll
        for (int ni = 0; ni < 4; ni++)
#pragma unroll
            for (int r = 0; r < 4; r++) {
                int row = m0 + mW + mi * 16 + quad * 4 + r;
                int col = n0 + nW + ni * 16 + lq;
                if (F32OUT)
                    ((float*)Cout)[(size_t)row * N + col] = acc[mi][ni][r];
                else
                    ((unsigned short*)Cout)[(size_t)row * N + col] = f2bf(acc[mi][ni][r]);
            }
}

// ---------------- attention constants ----------------
#define AT_T  1024
#define AT_B  8
#define AT_NH 16
#define AT_HS 3072
#define AT_ALPHA 0.18033688011112042f  // (1/8) * log2(e)

// ---------------- fused attention: one wave per (b, n, 16-row i-tile) ----------------
__global__ __launch_bounds__(64) void attn_fused(const unsigned short* __restrict__ heads,
                                                 unsigned short* __restrict__ av,
                                                 float* __restrict__ mBuf,
                                                 float* __restrict__ lBuf) {
    __shared__ alignas(16) unsigned short Ps[16][40];
    const int bn = blockIdx.x, b = bn >> 4, n = bn & 15;
    const int lane = threadIdx.x, quad = lane >> 4, lq = lane & 15;
    const int i0 = blockIdx.y * 16;

    size_t qbase = ((size_t)(i0 + lq) * 8 + b) * AT_HS + n * 64 + quad * 8;
    v8bf q0 = *(const v8bf*)(heads + qbase);
    v8bf q1 = *(const v8bf*)(heads + qbase + 32);

    // ---- pass 1: per-row max & sum (exp2 domain) ----
    float M[4], S[4];
#pragma unroll
    for (int r = 0; r < 4; r++) { M[r] = -1e30f; S[r] = 0.f; }

    for (int j0 = 0; j0 <= i0; j0 += 16) {
        size_t kbase = ((size_t)(j0 + lq) * 8 + b) * AT_HS + 1024 + n * 64 + quad * 8;
        v8bf k0 = *(const v8bf*)(heads + kbase);
        v8bf k1 = *(const v8bf*)(heads + kbase + 32);
        v4f s = (v4f){0.f, 0.f, 0.f, 0.f};
        s = MFMA16x16x32(q0, k0, s);
        s = MFMA16x16x32(q1, k1, s);
        int j = j0 + lq;
#pragma unroll
        for (int r = 0; r < 4; r++) {
            int i = i0 + quad * 4 + r;
            if (j <= i) {
                float v = s[r] * AT_ALPHA;
                float Mn = fmaxf(M[r], v);
                S[r] = S[r] * exp2f(M[r] - Mn) + exp2f(v - Mn);
                M[r] = Mn;
            }
        }
    }
#pragma unroll
    for (int mask = 1; mask < 16; mask <<= 1) {
#pragma unroll
        for (int r = 0; r < 4; r++) {
            float Mo = __shfl_xor(M[r], mask);
            float So = __shfl_xor(S[r], mask);
            float Mn = fmaxf(M[r], Mo);
            S[r] = S[r] * exp2f(M[r] - Mn) + So * exp2f(Mo - Mn);
            M[r] = Mn;
        }
    }
    float linv[4];
#pragma unroll
    for (int r = 0; r < 4; r++) linv[r] = __builtin_amdgcn_rcpf(S[r]);
    if (lq == 0) {
#pragma unroll
        for (int r = 0; r < 4; r++) {
            int i = i0 + quad * 4 + r;
            mBuf[(size_t)bn * AT_T + i] = M[r];
            lBuf[(size_t)bn * AT_T + i] = S[r];
        }
    }

    // ---- pass 2: O = P V over 32-j chunks ----
    v4f o[4];
#pragma unroll
    for (int dt = 0; dt < 4; dt++) o[dt] = (v4f){0.f, 0.f, 0.f, 0.f};

    for (int j0 = 0; j0 < i0 + 16; j0 += 32) {
#pragma unroll
        for (int jt = 0; jt < 2; jt++) {
            int jb = j0 + jt * 16;
            size_t kbase = ((size_t)(jb + lq) * 8 + b) * AT_HS + 1024 + n * 64 + quad * 8;
            v8bf k0 = *(const v8bf*)(heads + kbase);
            v8bf k1 = *(const v8bf*)(heads + kbase + 32);
            v4f s = (v4f){0.f, 0.f, 0.f, 0.f};
            s = MFMA16x16x32(q0, k0, s);
            s = MFMA16x16x32(q1, k1, s);
            int j = jb + lq;
#pragma unroll
            for (int r = 0; r < 4; r++) {
                int i = i0 + quad * 4 + r;
                float val = (j <= i) ? exp2f(s[r] * AT_ALPHA - M[r]) * linv[r] : 0.f;
                Ps[quad * 4 + r][jt * 16 + lq] = f2bf(val);
            }
        }
        __syncthreads();
        v8bf pf = *(const v8bf*)&Ps[lq][quad * 8];
#pragma unroll
        for (int dt = 0; dt < 4; dt++) {
            v8bf vf;
            unsigned short* vp = (unsigned short*)&vf;
#pragma unroll
            for (int jj = 0; jj < 8; jj++) {
                int j = j0 + quad * 8 + jj;
                vp[jj] = heads[((size_t)j * 8 + b) * AT_HS + 2048 + n * 64 + dt * 16 + lq];
            }
            o[dt] = MFMA16x16x32(pf, vf, o[dt]);
        }
        __syncthreads();   // Ps reused next chunk
    }

#pragma unroll
    for (int dt = 0; dt < 4; dt++)
#pragma unroll
        for (int r = 0; r < 4; r++) {
            int i = i0 + quad * 4 + r;
            av[((size_t)i * 8 + b) * 1024 + n * 64 + dt * 16 + lq] = f2bf(o[dt][r]);
        }
}

// ---------------- coverage2: cov[b][j][i] = mean_n prob[b,n,i,j] ----------------
// Block = (j-chunk of 8 tiles, i-tile, b); 4 waves, each owns 4 heads with Q-frags
// and softmax stats resident in registers for the whole block. Per j-tile: 8 K-loads,
// 8 MFMAs, cross-wave LDS reduce (pad-17, conflict-free), coalesced 64B writes.
// j-tiles above the diagonal write zeros directly (no separate memset pass).
__global__ __launch_bounds__(256) void coverage2(const unsigned short* __restrict__ heads,
                                                 const float* __restrict__ mBuf,
                                                 const float* __restrict__ lBuf,
                                                 float* __restrict__ cov) {
    __shared__ float red[4][16][17];
    const int jc = blockIdx.x, it = blockIdx.y, b = blockIdx.z;
    const int tid = threadIdx.x, wave = tid >> 6, lane = tid & 63;
    const int quad = lane >> 4, lq = lane & 15;
    const int i0 = it * 16;

    // Q-frags + stats for this wave's 4 heads (n = wave*4 + h), resident all block
    v8bf q0[4], q1[4];
    float mr[4][4], li[4][4];
#pragma unroll
    for (int h = 0; h < 4; h++) {
        int n = wave * 4 + h;
        size_t qbase = ((size_t)(i0 + lq) * 8 + b) * AT_HS + n * 64 + quad * 8;
        q0[h] = *(const v8bf*)(heads + qbase);
        q1[h] = *(const v8bf*)(heads + qbase + 32);
        int bn = b * 16 + n;
#pragma unroll
        for (int r = 0; r < 4; r++) {
            int i = i0 + quad * 4 + r;
            mr[h][r] = mBuf[(size_t)bn * AT_T + i];
            li[h][r] = __builtin_amdgcn_rcpf(lBuf[(size_t)bn * AT_T + i]);
        }
    }

    for (int jt = jc * 8; jt < jc * 8 + 8; jt++) {
        const int j0 = jt * 16;
        if (jt <= it) {
            v4f psum = (v4f){0.f, 0.f, 0.f, 0.f};
#pragma unroll
            for (int h = 0; h < 4; h++) {
                int n = wave * 4 + h;
                size_t kbase = ((size_t)(j0 + lq) * 8 + b) * AT_HS + 1024 + n * 64 + quad * 8;
                v8bf k0 = *(const v8bf*)(heads + kbase);
                v8bf k1 = *(const v8bf*)(heads + kbase + 32);
                v4f s = (v4f){0.f, 0.f, 0.f, 0.f};
                s = MFMA16x16x32(q0[h], k0, s);
                s = MFMA16x16x32(q1[h], k1, s);
                int j = j0 + lq;
#pragma unroll
                for (int r = 0; r < 4; r++) {
                    int i = i0 + quad * 4 + r;
                    if (j <= i)
                        psum[r] += exp2f(s[r] * AT_ALPHA - mr[h][r]) * li[h][r];
                }
            }
            __syncthreads();  // WAR: previous iteration's reads complete
#pragma unroll
            for (int r = 0; r < 4; r++) red[wave][quad * 4 + r][lq] = psum[r];
            __syncthreads();
            // wave w writes j-rows jl = quad*4 + w; i varies over lq (coalesced 64B)
            int jl = quad * 4 + wave;
            float v = (red[0][lq][jl] + red[1][lq][jl] + red[2][lq][jl] + red[3][lq][jl]) * 0.0625f;
            cov[(size_t)b * 1048576 + (size_t)(j0 + jl) * 1024 + i0 + lq] = v;
        } else {
            // upper-triangle tile: zeros (256 threads, 16 j-rows x 16 i)
            int jl = tid >> 4, il = tid & 15;
            cov[(size_t)b * 1048576 + (size_t)(j0 + jl) * 1024 + i0 + il] = 0.f;
        }
    }
}

// ---------------- launch ----------------
extern "C" void kernel_launch(void* const* d_in, const int* in_sizes, int n_in,
                              void* d_out, int out_size, void* d_ws, size_t ws_size,
                              hipStream_t stream) {
    const float* input = (const float*)d_in[0];
    const float* pos   = (const float*)d_in[1];
    // d_in[2] = attn_mask (deterministic causal; ignored)
    const float* Wqkv  = (const float*)d_in[3];
    const float* Wo    = (const float*)d_in[4];
    float* out = (float*)d_out;

    // workspace layout (bytes)
    char* ws = (char*)d_ws;
    if (ws_size < 93323264) return;  // need ~89 MB
    unsigned short* x     = (unsigned short*)(ws);               // 16,777,216 B
    unsigned short* heads = (unsigned short*)(ws + 16777216);    // 50,331,648 B
    unsigned short* av    = (unsigned short*)(ws + 67108864);    // 16,777,216 B
    unsigned short* WqkvT = (unsigned short*)(ws + 83886080);    //  6,291,456 B
    unsigned short* WoT   = (unsigned short*)(ws + 90177536);    //  2,097,152 B
    float* mBuf = (float*)(ws + 92274688);                       //    524,288 B
    float* lBuf = (float*)(ws + 92798976);                       //    524,288 B

    prep_x<<<4096, 256, 0, stream>>>(input, pos, x);
    transpose_f32_bf16<<<dim3(48, 16), 256, 0, stream>>>(Wqkv, WqkvT, 1024, 3072);
    transpose_f32_bf16<<<dim3(16, 16), 256, 0, stream>>>(Wo, WoT, 1024, 1024);
    gemm_bf16<false><<<dim3(24, 64), 256, 0, stream>>>(x, WqkvT, heads, 8192, 3072, 1024);
    attn_fused<<<dim3(128, 64), 64, 0, stream>>>(heads, av, mBuf, lBuf);
    coverage2<<<dim3(8, 64, 8), 256, 0, stream>>>(heads, mBuf, lBuf, out + 8388608);
    gemm_bf16<true><<<dim3(8, 64), 256, 0, stream>>>(av, WoT, out, 8388608 ? 8192 : 8192, 1024, 1024);
}